// Round 1
// baseline (300.557 us; speedup 1.0000x reference)
//
#include <hip/hip_runtime.h>
#include <math.h>

#define VIEWS 512
#define DETS  512

// derived constants (double, folded at compile time)
constexpr double S2R_D    = 5.95;
constexpr double D2R_D    = 4.906;
constexpr double DDET_D   = 0.0072;
constexpr double VIRDET_D = DDET_D * S2R_D / (S2R_D + D2R_D);
constexpr double DANG_D   = 2.0 * 3.14159265358979323846 / (double)VIEWS;

// ---------------------------------------------------------------------------
// Kernel 1: p = proj * w; ramp filter (exploiting zero even-offset taps);
// also writes the per-view cos/sin table (blocks 0,1).
// Grid: 512 blocks x 256 threads; each block = 2 rows, each row = 2 waves,
// each lane = 4 consecutive outputs.
// filtered[d] = sum_k pwpad[d+k]*filt[k], k in [0,1022], pw data at [511,1023).
// Nonzero taps: even k (sfe[e] = filt[2e]) plus center k=511.
// ---------------------------------------------------------------------------
__global__ __launch_bounds__(256) void fbp_filter_kernel(
    const float* __restrict__ proj, const float* __restrict__ wq,
    const float* __restrict__ filt, float* __restrict__ wsf,
    float* __restrict__ trig)
{
    __shared__ __align__(16) float pwpad[2][1536];
    __shared__ __align__(16) float sfe[520];
    const int tid = threadIdx.x;
    const int bid = blockIdx.x;              // 0..511

    if (bid < 2) {                           // trig table: 512 views
        int v = bid * 256 + tid;
        float beta = (float)DANG_D * (float)v;
        trig[v]         = cosf(beta);
        trig[VIEWS + v] = sinf(beta);
    }

    for (int i = tid; i < 520; i += 256)
        sfe[i] = (i < 512) ? filt[2 * i] : 0.0f;

    float4* pz = (float4*)&pwpad[0][0];      // 2*1536/4 = 768 float4
    #pragma unroll
    for (int i = 0; i < 3; ++i)
        pz[tid + 256 * i] = make_float4(0.f, 0.f, 0.f, 0.f);
    __syncthreads();

    {   // stage row data (128 threads per row), data region starts at 511
        const int rl  = tid >> 7;
        const int t2  = tid & 127;
        const int row = bid * 2 + rl;        // row = b*512 + v
        const float4 p4 = *(const float4*)(proj + (size_t)row * DETS + 4 * t2);
        const float4 w4 = *(const float4*)(wq + 4 * t2);
        pwpad[rl][511 + 4 * t2 + 0] = p4.x * w4.x;
        pwpad[rl][511 + 4 * t2 + 1] = p4.y * w4.y;
        pwpad[rl][511 + 4 * t2 + 2] = p4.z * w4.z;
        pwpad[rl][511 + 4 * t2 + 3] = p4.w * w4.w;
    }
    __syncthreads();

    const int lane = tid & 63;
    const int warp = tid >> 6;               // 0..3
    const int rl2  = warp >> 1;              // row within block
    const int wv   = warp & 1;               // wave within row
    const int d0   = 256 * wv + 4 * lane;    // first of 4 outputs
    const float* P = &pwpad[rl2][0];
    // per-wave trimmed even-tap range (divergence-free: uniform per wave)
    const int e_lo = wv ? 0 : 124;
    const int G    = wv ? 48 : 49;           // groups of 8 taps
    const float c0 = filt[511];              // center tap (scalar load)

    float a0 = 0.f, a1 = 0.f, a2 = 0.f, a3 = 0.f;
    for (int g = 0; g < G; ++g) {
        const int e0 = e_lo + 8 * g;
        const float4 S0 = *(const float4*)&sfe[e0];      // wave-uniform: broadcast
        const float4 S1 = *(const float4*)&sfe[e0 + 4];
        const float* Pb = P + d0 + 2 * e0;               // 16B aligned, lane stride 16B
        const float4 q0 = *(const float4*)(Pb + 0);
        const float4 q1 = *(const float4*)(Pb + 4);
        const float4 q2 = *(const float4*)(Pb + 8);
        const float4 q3 = *(const float4*)(Pb + 12);
        const float4 q4 = *(const float4*)(Pb + 16);
        const float p[20] = {q0.x,q0.y,q0.z,q0.w, q1.x,q1.y,q1.z,q1.w,
                             q2.x,q2.y,q2.z,q2.w, q3.x,q3.y,q3.z,q3.w,
                             q4.x,q4.y,q4.z,q4.w};
        const float s[8]  = {S0.x,S0.y,S0.z,S0.w, S1.x,S1.y,S1.z,S1.w};
        #pragma unroll
        for (int j = 0; j < 8; ++j) {        // acc[i] += pwpad[d0+i+2(e0+j)] * sfe[e0+j]
            a0 = fmaf(p[2*j + 0], s[j], a0);
            a1 = fmaf(p[2*j + 1], s[j], a1);
            a2 = fmaf(p[2*j + 2], s[j], a2);
            a3 = fmaf(p[2*j + 3], s[j], a3);
        }
    }
    // center tap k=511: filtered[d] += pw[d]*c0
    a0 = fmaf(P[511 + d0 + 0], c0, a0);
    a1 = fmaf(P[511 + d0 + 1], c0, a1);
    a2 = fmaf(P[511 + d0 + 2], c0, a2);
    a3 = fmaf(P[511 + d0 + 3], c0, a3);

    const int row2 = bid * 2 + rl2;
    *(float4*)(wsf + (size_t)row2 * DETS + d0) = make_float4(a0, a1, a2, a3);
}

// ---------------------------------------------------------------------------
// Kernel 2: single-view backprojection. Block = (v,y) row, thread = x.
// out[b,v,y,x] = wgt * bilinear(filtered[b,v,:], t) ; 256 MiB streaming store.
// ---------------------------------------------------------------------------
__global__ __launch_bounds__(256) void fbp_bp_kernel(
    const float* __restrict__ wsf, const float* __restrict__ trig,
    float* __restrict__ out)
{
    const int v = blockIdx.x >> 8;           // scalar
    const int y = blockIdx.x & 255;          // scalar
    const int x = threadIdx.x;
    const float cb = trig[v];                // uniform -> s_load
    const float sb = trig[VIEWS + v];
    const float xs = ((float)x - 127.5f) * 0.006641f;
    const float ys = (127.5f - (float)y) * 0.006641f;
    const float den = 5.95f - (xs * cb + ys * sb);
    float inv = __builtin_amdgcn_rcpf(den);
    inv = inv * (2.0f - den * inv);          // 1 Newton step
    const float sw  = 5.95f * inv;
    const float wgt = sw * sw;
    const float u   = 5.95f * (ys * cb - xs * sb) * inv;
    const float t   = u * (float)(1.0 / VIRDET_D) + 255.5f;
    const float ft  = floorf(t);
    const int   i0  = (int)ft;
    const float fr  = t - ft;
    const float w0 = (i0 >= 0 && i0 < DETS)         ? (1.0f - fr) : 0.0f;
    const float w1 = (i0 + 1 >= 0 && i0 + 1 < DETS) ? fr          : 0.0f;
    const int i0c = min(max(i0, 0), DETS - 1);
    const int i1c = min(max(i0 + 1, 0), DETS - 1);
    const float* r0 = wsf + ((size_t)v << 9);            // batch 0 row
    const float* r1 = wsf + ((size_t)(VIEWS + v) << 9);  // batch 1 row
    const float o0 = wgt * (r0[i0c] * w0 + r0[i1c] * w1);
    const float o1 = wgt * (r1[i0c] * w0 + r1[i1c] * w1);
    const size_t pix = ((size_t)blockIdx.x << 8) + (size_t)x;  // v*65536+y*256+x
    __builtin_nontemporal_store(o0, out + pix);
    __builtin_nontemporal_store(o1, out + 33554432u + pix);
}

extern "C" void kernel_launch(void* const* d_in, const int* in_sizes, int n_in,
                              void* d_out, int out_size, void* d_ws, size_t ws_size,
                              hipStream_t stream) {
    const float* proj = (const float*)d_in[0];   // (2,1,512,512)
    const float* wq   = (const float*)d_in[1];   // (512,)
    const float* filt = (const float*)d_in[2];   // (1023,)
    float* out  = (float*)d_out;                 // (2,512,256,256)
    float* wsf  = (float*)d_ws;                  // filtered: 1024*512 floats
    float* trig = wsf + (size_t)1024 * 512;      // cos[512] then sin[512]

    hipLaunchKernelGGL(fbp_filter_kernel, dim3(512), dim3(256), 0, stream,
                       proj, wq, filt, wsf, trig);
    hipLaunchKernelGGL(fbp_bp_kernel, dim3(VIEWS * 256), dim3(256), 0, stream,
                       wsf, trig, out);
}

// Round 2
// 287.887 us; speedup vs baseline: 1.0440x; 1.0440x over previous
//
#include <hip/hip_runtime.h>
#include <math.h>

#define VIEWS 512
#define DETS  512

typedef float f32x4 __attribute__((ext_vector_type(4)));

// derived constants (double, folded at compile time)
constexpr double S2R_D    = 5.95;
constexpr double D2R_D    = 4.906;
constexpr double DDET_D   = 0.0072;
constexpr double VIRDET_D = DDET_D * S2R_D / (S2R_D + D2R_D);
constexpr double DANG_D   = 2.0 * 3.14159265358979323846 / (double)VIEWS;

// ---------------------------------------------------------------------------
// Kernel 1: p = proj * w; ramp filter (exploiting zero even-offset taps);
// also writes the per-view cos/sin table (blocks 0,1).
// Grid: 512 blocks x 256 threads; each block = 2 rows, each row = 2 waves,
// each lane = 4 consecutive outputs.
// ---------------------------------------------------------------------------
__global__ __launch_bounds__(256) void fbp_filter_kernel(
    const float* __restrict__ proj, const float* __restrict__ wq,
    const float* __restrict__ filt, float* __restrict__ wsf,
    float* __restrict__ trig)
{
    __shared__ __align__(16) float pwpad[2][1536];
    __shared__ __align__(16) float sfe[520];
    const int tid = threadIdx.x;
    const int bid = blockIdx.x;              // 0..511

    if (bid < 2) {                           // trig table: 512 views
        int v = bid * 256 + tid;
        float beta = (float)DANG_D * (float)v;
        trig[v]         = cosf(beta);
        trig[VIEWS + v] = sinf(beta);
    }

    for (int i = tid; i < 520; i += 256)
        sfe[i] = (i < 512) ? filt[2 * i] : 0.0f;

    float4* pz = (float4*)&pwpad[0][0];      // 2*1536/4 = 768 float4
    #pragma unroll
    for (int i = 0; i < 3; ++i)
        pz[tid + 256 * i] = make_float4(0.f, 0.f, 0.f, 0.f);
    __syncthreads();

    {   // stage row data (128 threads per row), data region starts at 511
        const int rl  = tid >> 7;
        const int t2  = tid & 127;
        const int row = bid * 2 + rl;        // row = b*512 + v
        const float4 p4 = *(const float4*)(proj + (size_t)row * DETS + 4 * t2);
        const float4 w4 = *(const float4*)(wq + 4 * t2);
        pwpad[rl][511 + 4 * t2 + 0] = p4.x * w4.x;
        pwpad[rl][511 + 4 * t2 + 1] = p4.y * w4.y;
        pwpad[rl][511 + 4 * t2 + 2] = p4.z * w4.z;
        pwpad[rl][511 + 4 * t2 + 3] = p4.w * w4.w;
    }
    __syncthreads();

    const int lane = tid & 63;
    const int warp = tid >> 6;               // 0..3
    const int rl2  = warp >> 1;              // row within block
    const int wv   = warp & 1;               // wave within row
    const int d0   = 256 * wv + 4 * lane;    // first of 4 outputs
    const float* P = &pwpad[rl2][0];
    // per-wave trimmed even-tap range (divergence-free: uniform per wave)
    const int e_lo = wv ? 0 : 124;
    const int G    = wv ? 48 : 49;           // groups of 8 taps
    const float c0 = filt[511];              // center tap (scalar load)

    float a0 = 0.f, a1 = 0.f, a2 = 0.f, a3 = 0.f;
    for (int g = 0; g < G; ++g) {
        const int e0 = e_lo + 8 * g;
        const float4 S0 = *(const float4*)&sfe[e0];      // wave-uniform: broadcast
        const float4 S1 = *(const float4*)&sfe[e0 + 4];
        const float* Pb = P + d0 + 2 * e0;               // 16B aligned, lane stride 16B
        const float4 q0 = *(const float4*)(Pb + 0);
        const float4 q1 = *(const float4*)(Pb + 4);
        const float4 q2 = *(const float4*)(Pb + 8);
        const float4 q3 = *(const float4*)(Pb + 12);
        const float4 q4 = *(const float4*)(Pb + 16);
        const float p[20] = {q0.x,q0.y,q0.z,q0.w, q1.x,q1.y,q1.z,q1.w,
                             q2.x,q2.y,q2.z,q2.w, q3.x,q3.y,q3.z,q3.w,
                             q4.x,q4.y,q4.z,q4.w};
        const float s[8]  = {S0.x,S0.y,S0.z,S0.w, S1.x,S1.y,S1.z,S1.w};
        #pragma unroll
        for (int j = 0; j < 8; ++j) {
            a0 = fmaf(p[2*j + 0], s[j], a0);
            a1 = fmaf(p[2*j + 1], s[j], a1);
            a2 = fmaf(p[2*j + 2], s[j], a2);
            a3 = fmaf(p[2*j + 3], s[j], a3);
        }
    }
    // center tap k=511
    a0 = fmaf(P[511 + d0 + 0], c0, a0);
    a1 = fmaf(P[511 + d0 + 1], c0, a1);
    a2 = fmaf(P[511 + d0 + 2], c0, a2);
    a3 = fmaf(P[511 + d0 + 3], c0, a3);

    const int row2 = bid * 2 + rl2;
    *(float4*)(wsf + (size_t)row2 * DETS + d0) = make_float4(a0, a1, a2, a3);
}

// ---------------------------------------------------------------------------
// Kernel 2: single-view backprojection, fat blocks.
// Grid: 512 views x 8 y-chunks = 4096 blocks, 256 threads.
// Block stages both batches' filtered rows (4 KB) in LDS, then each wave
// emits one full y-row (64 lanes x float4 = 256 x) per iteration, 8 iters.
// ---------------------------------------------------------------------------
__global__ __launch_bounds__(256) void fbp_bp_kernel(
    const float* __restrict__ wsf, const float* __restrict__ trig,
    float* __restrict__ out)
{
    __shared__ __align__(16) float rows[2][DETS];
    const int tid = threadIdx.x;
    const int v  = blockIdx.x >> 3;          // uniform
    const int yc = blockIdx.x & 7;           // uniform

    {   // stage rows: threads 0..127 -> batch0, 128..255 -> batch1
        const float* src = wsf + (((size_t)(tid >> 7) * VIEWS + v) << 9);
        ((float4*)&rows[0][0])[tid] = ((const float4*)src)[tid & 127];
    }
    const float cb = trig[v];                // uniform -> scalar
    const float sb = trig[VIEWS + v];
    __syncthreads();

    const int xi = (tid & 63) * 4;           // first of 4 x values
    const int wv = tid >> 6;                 // wave id = row offset 0..3
    const float xs0 = ((float)xi - 127.5f) * 0.006641f;
    const float xc0 = xs0 * cb;              // x*cb terms, step D*cb
    const float xs_sb0 = xs0 * sb;
    const float dcb = 0.006641f * cb;
    const float dsb = 0.006641f * sb;

    #pragma unroll
    for (int i = 0; i < 8; ++i) {
        const int y = yc * 32 + i * 4 + wv;  // wave-uniform
        const float ys = (127.5f - (float)y) * 0.006641f;
        const float ysb = ys * sb;           // scalar
        const float ycb = ys * cb;           // scalar
        f32x4 o0, o1;
        #pragma unroll
        for (int j = 0; j < 4; ++j) {
            const float xcb = xc0 + (float)j * dcb;
            const float xsb = xs_sb0 + (float)j * dsb;
            const float den = 5.95f - xcb - ysb;
            float inv = __builtin_amdgcn_rcpf(den);
            inv = inv * (2.0f - den * inv);  // 1 Newton step
            const float sw  = 5.95f * inv;
            const float wgt = sw * sw;
            const float u   = 5.95f * (ycb - xsb) * inv;
            const float t   = u * (float)(1.0 / VIRDET_D) + 255.5f;
            const float ft  = floorf(t);
            const int   i0  = (int)ft;
            const float fr  = t - ft;
            const float w0 = (i0 >= 0 && i0 < DETS)         ? (1.0f - fr) : 0.0f;
            const float w1 = (i0 + 1 >= 0 && i0 + 1 < DETS) ? fr          : 0.0f;
            const int i0c = min(max(i0, 0), DETS - 1);
            const int i1c = min(max(i0 + 1, 0), DETS - 1);
            o0[j] = wgt * (rows[0][i0c] * w0 + rows[0][i1c] * w1);
            o1[j] = wgt * (rows[1][i0c] * w0 + rows[1][i1c] * w1);
        }
        const size_t pix = (((size_t)v << 16) + ((size_t)y << 8) + (size_t)xi) >> 2;
        __builtin_nontemporal_store(o0, (f32x4*)out + pix);
        __builtin_nontemporal_store(o1, (f32x4*)out + 8388608u + pix);
    }
}

extern "C" void kernel_launch(void* const* d_in, const int* in_sizes, int n_in,
                              void* d_out, int out_size, void* d_ws, size_t ws_size,
                              hipStream_t stream) {
    const float* proj = (const float*)d_in[0];   // (2,1,512,512)
    const float* wq   = (const float*)d_in[1];   // (512,)
    const float* filt = (const float*)d_in[2];   // (1023,)
    float* out  = (float*)d_out;                 // (2,512,256,256)
    float* wsf  = (float*)d_ws;                  // filtered: 1024*512 floats
    float* trig = wsf + (size_t)1024 * 512;      // cos[512] then sin[512]

    hipLaunchKernelGGL(fbp_filter_kernel, dim3(512), dim3(256), 0, stream,
                       proj, wq, filt, wsf, trig);
    hipLaunchKernelGGL(fbp_bp_kernel, dim3(VIEWS * 8), dim3(256), 0, stream,
                       wsf, trig, out);
}